// Round 18
// baseline (125.460 us; speedup 1.0000x reference)
//
#include <hip/hip_runtime.h>
#include <stdint.h>

// ---------------------------------------------------------------------------
// UnifiedEnergyFunction: total/hopfield/consistency/regularization scalars.
//   hopfield = mean_b( -logsumexp_n( z[b,:] . M[n,:] ) )
//   consistency = mean_b ||z - z_next||^2
//   regularization = 0.01 * mean_b ||z||^2
// v18: ONE WAVE PER SIMD (pure-ILP regime). All multi-wave schedules
// (v13 2w, v16 4w, v17 prod/cons) phase-lock into additive MFMA+VALU.
// Here: 256 blocks (1/CU) x 4 waves (1/SIMD); each wave owns 64 b-cols and
// the full 256-group range; the 4 waves share one af stream (L1-friendly).
// In-wave ILP overlaps: MFMA(CUR) issue -> af refill (2-group-ahead) ->
// exp2 drain of PREV (complete, independent). INITC as MFMA C-in, no
// setprio, no barriers. MX-fp8 16x16x128, scale=1.0 (v13 numerics).
// ---------------------------------------------------------------------------

typedef __attribute__((ext_vector_type(8))) int   v8i;
typedef __attribute__((ext_vector_type(4))) float f32x4;

#define N_PAT  65536
#define D_DIM  256
#define B_ROWS 4096
#define NSPLIT 16                 // M ranges (2 per XCD, 1MB fp8 each)
#define NRANGE (N_PAT / NSPLIT)   // 4096 rows per range
#define SPR    (NRANGE / 16)      // 256 16-row fragment groups per range
#define BBLK   256                // b rows per block (4 waves x 64)
#define SHIFT2 69.0f              // fixed shift in log2 domain (~48 nats)
#define LOG2E  1.44269504f
#define LN2    0.69314718f
#define SCL1   0x7F7F7F7F         // E8M0 scale bytes = 127 -> 1.0

// workspace layout (bytes)
#define WS_M_OFF   ((size_t)0)
#define WS_M_BYTES ((size_t)N_PAT * D_DIM)          // 16 MB packed fp8 M
#define WS_Z_OFF   (WS_M_OFF + WS_M_BYTES)
#define WS_Z_BYTES ((size_t)B_ROWS * D_DIM)         // 1 MB fp8 z*log2e
#define WS_LSE_OFF (WS_Z_OFF + WS_Z_BYTES)
#define WS_LSE_BYTES ((size_t)B_ROWS * NSPLIT * 4)  // 256KB partial S
#define WS_ROW_OFF (WS_LSE_OFF + WS_LSE_BYTES)
#define WS_ROW_BYTES ((size_t)B_ROWS * 4)           // 16KB per-row lse
#define WS_CSS_OFF (WS_ROW_OFF + WS_ROW_BYTES)
#define WS_ZSS_OFF (WS_CSS_OFF + (size_t)512 * 4)

__device__ __forceinline__ float fexp2(float x) {
  return __builtin_amdgcn_exp2f(x);   // v_exp_f32 (hardware base-2 exp)
}

__device__ __forceinline__ int pk4_fp8(float a, float b, float c, float d) {
  int r = __builtin_amdgcn_cvt_pk_fp8_f32(a, b, 0, false);   // bytes 0,1
  r = __builtin_amdgcn_cvt_pk_fp8_f32(c, d, r, true);        // bytes 2,3
  return r;
}

__device__ __forceinline__ float waveRedAdd(float v) {
  #pragma unroll
  for (int o = 32; o > 0; o >>= 1) v += __shfl_down(v, o, 64);
  return v;
}

// ---------------------------------------------------------------- kernel A1
// M f32 -> fp8 e4m3 in 16x16x128 A-fragment order, coalesced reads.
// Element M[row][k] -> dword (row>>4)*1024 + (k>>7)*512 +
//   (((k>>5)&3)*16 + (row&15))*8 + ((k>>2)&7)  [byte k&3]
__global__ void convert_m_kernel(const float* __restrict__ src, int* __restrict__ dst) {
  const int c = blockIdx.x * 256 + threadIdx.x;   // chunk 0..2^21-1 (grid 8192)
  const int row = c >> 5;
  const int j = c & 31;                           // which 8-elem chunk of the row
  const float* sp = src + (size_t)row * D_DIM + j * 8;
  const float4 x = *(const float4*)(sp);
  const float4 y = *(const float4*)(sp + 4);
  int2 o;
  o.x = pk4_fp8(x.x, x.y, x.z, x.w);
  o.y = pk4_fp8(y.x, y.y, y.z, y.w);
  const size_t dw = (size_t)(row >> 4) * 1024 + (j >> 4) * 512 +
                    (((j >> 2) & 3) * 16 + (row & 15)) * 8 + (j & 3) * 2;
  *(int2*)(dst + dw) = o;
}

// ---------------------------------------------------------------- kernel A2
// z -> fp8 of z*log2(e) (row-major), plus partials of ||z-zn||^2, ||z||^2
__global__ void prep_z_kernel(const float* __restrict__ z, const float* __restrict__ zn,
                              int* __restrict__ z8, float* __restrict__ css,
                              float* __restrict__ zss) {
  int t = blockIdx.x * 256 + threadIdx.x;  // 512 blocks x 256 = exactly B*D/8
  const float* az = z + (size_t)t * 8;
  const float* an = zn + (size_t)t * 8;
  float4 z0 = *(const float4*)(az), z1 = *(const float4*)(az + 4);
  float4 n0 = *(const float4*)(an), n1 = *(const float4*)(an + 4);
  float zv[8] = {z0.x, z0.y, z0.z, z0.w, z1.x, z1.y, z1.z, z1.w};
  float nv[8] = {n0.x, n0.y, n0.z, n0.w, n1.x, n1.y, n1.z, n1.w};
  float cs = 0.f, zs = 0.f;
  #pragma unroll
  for (int j = 0; j < 8; ++j) {
    float d = zv[j] - nv[j];
    cs += d * d;
    zs += zv[j] * zv[j];
  }
  int2 o;
  o.x = pk4_fp8(zv[0] * LOG2E, zv[1] * LOG2E, zv[2] * LOG2E, zv[3] * LOG2E);
  o.y = pk4_fp8(zv[4] * LOG2E, zv[5] * LOG2E, zv[6] * LOG2E, zv[7] * LOG2E);
  *(int2*)(z8 + (size_t)t * 2) = o;        // row-major fp8, 8 bytes/thread

  __shared__ float rc[4], rz[4];
  cs = waveRedAdd(cs);
  zs = waveRedAdd(zs);
  int w = threadIdx.x >> 6, lane = threadIdx.x & 63;
  if (lane == 0) { rc[w] = cs; rz[w] = zs; }
  __syncthreads();
  if (threadIdx.x == 0) {
    css[blockIdx.x] = rc[0] + rc[1] + rc[2] + rc[3];
    zss[blockIdx.x] = rz[0] + rz[1] + rz[2] + rz[3];
  }
}

// ---------------------------------------------------------------- kernel B
// Barrier-free flash-LSE, MX-fp8 16x16x128 (scale=1.0).
// 256 blocks x 4 waves = 1 block/CU, 1 wave/SIMD (pure-ILP regime).
// Wave w owns b-cols [bblk*256 + w*64, +64); all waves walk the same
// 256-group sequence (shared af stream -> L1 hits for 3 of 4 waves).
// Per group: {8 MFMA (INITC C-in) | refill af 2-ahead | drain PREV 16 exp2}.
__global__ __launch_bounds__(256, 1) void lse_kernel(const int* __restrict__ Mp,
                                                     const int* __restrict__ z8,
                                                     float* __restrict__ lsep) {
  const int bid = blockIdx.x;             // 256 blocks
  const int xcd = bid & 7;
  const int g = bid >> 3;                 // 0..31
  const int bblk = g & 15;                // 16 b-blocks of 256 rows
  const int half = g >> 4;
  const int nsplit = xcd * 2 + half;      // 2 ranges live per XCD (proven)

  const int tid = threadIdx.x;
  const int w = tid >> 6;
  const int lane = tid & 63;
  const int l15 = lane & 15;
  const int grp = lane >> 4;

  // hoist z fragments: 4 b-subtiles x 2 k-halves = 64 regs
  v8i zf[4][2];
  const int brow0 = bblk * BBLK + w * 64;
  #pragma unroll
  for (int bt = 0; bt < 4; ++bt) {
    #pragma unroll
    for (int kh = 0; kh < 2; ++kh) {
      int row = brow0 + bt * 16 + l15;
      zf[bt][kh] = *(const v8i*)(z8 + (size_t)row * 64 + kh * 32 + grp * 8);
    }
  }

  // fragment stream: s = nsplit*256 + j; dword(s,kh,lane) = s*1024+kh*512+lane*8
  const int* pj = Mp + (size_t)nsplit * SPR * 1024 + lane * 8;

  const f32x4 INITC = {-SHIFT2, -SHIFT2, -SHIFT2, -SHIFT2};
  float ssum[4] = {0.f, 0.f, 0.f, 0.f};
  f32x4 accA[4], accB[4];
  v8i afA[2], afB[2];

  // accB pre-drained state: -inf so the first (dummy) drain adds exp2(-inf)=0
  #pragma unroll
  for (int bt = 0; bt < 4; ++bt)
    #pragma unroll
    for (int q = 0; q < 4; ++q) accB[bt][q] = -INFINITY;

  // prologue: groups 0 and 1 in flight (2-deep prefetch)
  #pragma unroll
  for (int kh = 0; kh < 2; ++kh) afA[kh] = *(const v8i*)(pj + kh * 512);
  #pragma unroll
  for (int kh = 0; kh < 2; ++kh) afB[kh] = *(const v8i*)(pj + 1024 + kh * 512);

  // body: MFMA with F (group j), refill F with group j+2 (~550cy slack),
  // drain PREV (group j-1's acc — complete, independent of in-flight MFMAs)
  auto body = [&](f32x4 (&CUR)[4], f32x4 (&PREV)[4], v8i (&F)[2]) {
    #pragma unroll
    for (int bt = 0; bt < 4; ++bt)        // kh=0: INITC as C-in (no init movs)
      CUR[bt] = __builtin_amdgcn_mfma_scale_f32_16x16x128_f8f6f4(
          F[0], zf[bt][0], INITC, 0, 0, 0, SCL1, 0, SCL1);
    #pragma unroll
    for (int bt = 0; bt < 4; ++bt)        // kh=1: accumulate
      CUR[bt] = __builtin_amdgcn_mfma_scale_f32_16x16x128_f8f6f4(
          F[1], zf[bt][1], CUR[bt], 0, 0, 0, SCL1, 0, SCL1);

    // refill F for group j+2 (WAR-safe: in-order issue after the MFMAs;
    // tail overshoot lands in the z8 region of d_ws: harmless)
    const int* p2 = pj + 2048;
    #pragma unroll
    for (int kh = 0; kh < 2; ++kh) F[kh] = *(const v8i*)(p2 + kh * 512);

    // drain PREVIOUS group's accumulator on the trans pipe
    #pragma unroll
    for (int bt = 0; bt < 4; ++bt)
      ssum[bt] += (fexp2(PREV[bt][0]) + fexp2(PREV[bt][1])) +
                  (fexp2(PREV[bt][2]) + fexp2(PREV[bt][3]));

    pj += 1024;
  };

  #pragma unroll 1
  for (int jp = 0; jp < SPR / 2; ++jp) {
    body(accA, accB, afA);   // even group: compute A (frags afA), drain B
    body(accB, accA, afB);   // odd group:  compute B (frags afB), drain A
  }

  // final drain (accB computed last)
  #pragma unroll
  for (int bt = 0; bt < 4; ++bt)
    ssum[bt] += (fexp2(accB[bt][0]) + fexp2(accB[bt][1])) +
                (fexp2(accB[bt][2]) + fexp2(accB[bt][3]));

  // 4 lane-groups hold different n-rows of each fragment for the same b-col
  #pragma unroll
  for (int bt = 0; bt < 4; ++bt) {
    ssum[bt] += __shfl_xor(ssum[bt], 16, 64);
    ssum[bt] += __shfl_xor(ssum[bt], 32, 64);
  }
  if (grp == 0) {
    #pragma unroll
    for (int bt = 0; bt < 4; ++bt) {
      int b = brow0 + bt * 16 + l15;
      lsep[(size_t)b * NSPLIT + nsplit] = ssum[bt];
    }
  }
}

// ---------------------------------------------------------------- kernel C1
// per-row logsumexp partial combine (parallel: 16 blocks x 256 = 4096 rows)
__global__ void rowlse_kernel(const float* __restrict__ lsep, float* __restrict__ rowlse) {
  int r = blockIdx.x * 256 + threadIdx.x;
  float S = 0.f;
  #pragma unroll
  for (int i = 0; i < NSPLIT; ++i) S += lsep[(size_t)r * NSPLIT + i];
  rowlse[r] = SHIFT2 * LN2 + logf(S);
}

// ---------------------------------------------------------------- kernel C2
__global__ void finalize_kernel(const float* __restrict__ rowlse, const float* __restrict__ css,
                                const float* __restrict__ zss, float* __restrict__ out) {
  __shared__ float r1[16], r2[16], r3[16];
  int tid = threadIdx.x;  // 1024
  float sum_lse = 0.f;
  #pragma unroll
  for (int i = 0; i < 4; ++i) sum_lse += rowlse[tid + i * 1024];
  float cs = 0.f, zs = 0.f;
  if (tid < 512) { cs = css[tid]; zs = zss[tid]; }

  sum_lse = waveRedAdd(sum_lse);
  cs = waveRedAdd(cs);
  zs = waveRedAdd(zs);
  int w = tid >> 6, lane = tid & 63;
  if (lane == 0) { r1[w] = sum_lse; r2[w] = cs; r3[w] = zs; }
  __syncthreads();
  if (tid == 0) {
    float sl = 0.f, sc = 0.f, sz = 0.f;
    #pragma unroll
    for (int i = 0; i < 16; ++i) { sl += r1[i]; sc += r2[i]; sz += r3[i]; }
    float hop = -sl / (float)B_ROWS;
    float cons = sc / (float)B_ROWS;
    float reg = 0.01f * sz / (float)B_ROWS;
    out[0] = hop + cons + reg;
    out[1] = hop;
    out[2] = cons;
    out[3] = reg;
  }
}

// ---------------------------------------------------------------------------
extern "C" void kernel_launch(void* const* d_in, const int* in_sizes, int n_in,
                              void* d_out, int out_size, void* d_ws, size_t ws_size,
                              hipStream_t stream) {
  (void)in_sizes; (void)n_in; (void)out_size; (void)ws_size;
  const float* z  = (const float*)d_in[0];
  const float* zn = (const float*)d_in[1];
  const float* M  = (const float*)d_in[2];
  char* ws = (char*)d_ws;
  int* Mp  = (int*)(ws + WS_M_OFF);
  int* z8  = (int*)(ws + WS_Z_OFF);
  float* lsep = (float*)(ws + WS_LSE_OFF);
  float* rowlse = (float*)(ws + WS_ROW_OFF);
  float* css = (float*)(ws + WS_CSS_OFF);
  float* zss = (float*)(ws + WS_ZSS_OFF);

  convert_m_kernel<<<8192, 256, 0, stream>>>(M, Mp);
  prep_z_kernel<<<512, 256, 0, stream>>>(z, zn, z8, css, zss);
  lse_kernel<<<256, 256, 0, stream>>>(Mp, z8, lsep);
  rowlse_kernel<<<16, 256, 0, stream>>>(lsep, rowlse);
  finalize_kernel<<<1, 1024, 0, stream>>>(rowlse, css, zss, (float*)d_out);
}

// Round 19
// 83.883 us; speedup vs baseline: 1.4957x; 1.4957x over previous
//
#include <hip/hip_runtime.h>
#include <stdint.h>

// ---------------------------------------------------------------------------
// UnifiedEnergyFunction: total/hopfield/consistency/regularization scalars.
//   hopfield = mean_b( -logsumexp_n( z[b,:] . M[n,:] ) )
//   consistency = mean_b ||z - z_next||^2
//   regularization = 0.01 * mean_b ||z||^2
// v19 (final assembly) = v13 (session best: MX-fp8 16x16x128 barrier-free
// stream, 2 waves/SIMD, double accumulator, setprio, 64.7us lse) plus the
// three individually-proven work-reductions:
//   - INITC as MFMA C-in (v16): removes 16 acc-init movs per group
//   - coalesced convert_m (v14/v15): layout-identical, ~2x faster converter
//   - split finalize (v17): parallel rowlse pass instead of 512KB single-block
// Rationale: 6 structural experiments (v6,v14,v15,v16,v17,v18) show the
// MFMA and VALU/trans phases run ADDITIVELY on this workload regardless of
// scheduling; remaining gains = removing work, which this does.
// ---------------------------------------------------------------------------

typedef __attribute__((ext_vector_type(8))) int   v8i;
typedef __attribute__((ext_vector_type(4))) float f32x4;

#define N_PAT  65536
#define D_DIM  256
#define B_ROWS 4096
#define NSPLIT 16                 // M ranges (2 per XCD, 1MB fp8 each)
#define NRANGE (N_PAT / NSPLIT)   // 4096 rows per range
#define SPR    (NRANGE / 16)      // 256 16-row fragment groups per range
#define SPERW  (SPR / 2)          // 128 groups per wave (nh parity split)
#define BBLK   128                // b rows per block (2 bh x 64)
#define NPART  (NSPLIT * 2)       // 32 partials per b row
#define SHIFT2 69.0f              // fixed shift in log2 domain (~48 nats)
#define LOG2E  1.44269504f
#define LN2    0.69314718f
#define SCL1   0x7F7F7F7F         // E8M0 scale bytes = 127 -> 1.0

// workspace layout (bytes)
#define WS_M_OFF   ((size_t)0)
#define WS_M_BYTES ((size_t)N_PAT * D_DIM)          // 16 MB packed fp8 M
#define WS_Z_OFF   (WS_M_OFF + WS_M_BYTES)
#define WS_Z_BYTES ((size_t)B_ROWS * D_DIM)         // 1 MB fp8 z*log2e
#define WS_LSE_OFF (WS_Z_OFF + WS_Z_BYTES)
#define WS_LSE_BYTES ((size_t)B_ROWS * NPART * 4)   // 512KB partial S
#define WS_ROW_OFF (WS_LSE_OFF + WS_LSE_BYTES)
#define WS_ROW_BYTES ((size_t)B_ROWS * 4)           // 16KB per-row lse
#define WS_CSS_OFF (WS_ROW_OFF + WS_ROW_BYTES)
#define WS_ZSS_OFF (WS_CSS_OFF + (size_t)512 * 4)

__device__ __forceinline__ float fexp2(float x) {
  return __builtin_amdgcn_exp2f(x);   // v_exp_f32 (hardware base-2 exp)
}

__device__ __forceinline__ int pk4_fp8(float a, float b, float c, float d) {
  int r = __builtin_amdgcn_cvt_pk_fp8_f32(a, b, 0, false);   // bytes 0,1
  r = __builtin_amdgcn_cvt_pk_fp8_f32(c, d, r, true);        // bytes 2,3
  return r;
}

__device__ __forceinline__ float waveRedAdd(float v) {
  #pragma unroll
  for (int o = 32; o > 0; o >>= 1) v += __shfl_down(v, o, 64);
  return v;
}

// ---------------------------------------------------------------- kernel A1
// M f32 -> fp8 e4m3 in 16x16x128 A-fragment order, coalesced reads.
// Element M[row][k] -> dword (row>>4)*1024 + (k>>7)*512 +
//   (((k>>5)&3)*16 + (row&15))*8 + ((k>>2)&7)  [byte k&3]
__global__ void convert_m_kernel(const float* __restrict__ src, int* __restrict__ dst) {
  const int c = blockIdx.x * 256 + threadIdx.x;   // chunk 0..2^21-1 (grid 8192)
  const int row = c >> 5;
  const int j = c & 31;                           // which 8-elem chunk of the row
  const float* sp = src + (size_t)row * D_DIM + j * 8;
  const float4 x = *(const float4*)(sp);
  const float4 y = *(const float4*)(sp + 4);
  int2 o;
  o.x = pk4_fp8(x.x, x.y, x.z, x.w);
  o.y = pk4_fp8(y.x, y.y, y.z, y.w);
  const size_t dw = (size_t)(row >> 4) * 1024 + (j >> 4) * 512 +
                    (((j >> 2) & 3) * 16 + (row & 15)) * 8 + (j & 3) * 2;
  *(int2*)(dst + dw) = o;
}

// ---------------------------------------------------------------- kernel A2
// z -> fp8 of z*log2(e) (row-major), plus partials of ||z-zn||^2, ||z||^2
__global__ void prep_z_kernel(const float* __restrict__ z, const float* __restrict__ zn,
                              int* __restrict__ z8, float* __restrict__ css,
                              float* __restrict__ zss) {
  int t = blockIdx.x * 256 + threadIdx.x;  // 512 blocks x 256 = exactly B*D/8
  const float* az = z + (size_t)t * 8;
  const float* an = zn + (size_t)t * 8;
  float4 z0 = *(const float4*)(az), z1 = *(const float4*)(az + 4);
  float4 n0 = *(const float4*)(an), n1 = *(const float4*)(an + 4);
  float zv[8] = {z0.x, z0.y, z0.z, z0.w, z1.x, z1.y, z1.z, z1.w};
  float nv[8] = {n0.x, n0.y, n0.z, n0.w, n1.x, n1.y, n1.z, n1.w};
  float cs = 0.f, zs = 0.f;
  #pragma unroll
  for (int j = 0; j < 8; ++j) {
    float d = zv[j] - nv[j];
    cs += d * d;
    zs += zv[j] * zv[j];
  }
  int2 o;
  o.x = pk4_fp8(zv[0] * LOG2E, zv[1] * LOG2E, zv[2] * LOG2E, zv[3] * LOG2E);
  o.y = pk4_fp8(zv[4] * LOG2E, zv[5] * LOG2E, zv[6] * LOG2E, zv[7] * LOG2E);
  *(int2*)(z8 + (size_t)t * 2) = o;        // row-major fp8, 8 bytes/thread

  __shared__ float rc[4], rz[4];
  cs = waveRedAdd(cs);
  zs = waveRedAdd(zs);
  int w = threadIdx.x >> 6, lane = threadIdx.x & 63;
  if (lane == 0) { rc[w] = cs; rz[w] = zs; }
  __syncthreads();
  if (threadIdx.x == 0) {
    css[blockIdx.x] = rc[0] + rc[1] + rc[2] + rc[3];
    zss[blockIdx.x] = rz[0] + rz[1] + rz[2] + rz[3];
  }
}

// ---------------------------------------------------------------- kernel B
// Barrier-free flash-LSE, MX-fp8 16x16x128 (scale=1.0), 512 blocks x 4 waves,
// 2 blocks/CU (v13 structure). Wave = (bh, nh): 64 b-cols (zf[4][2] = 64
// regs), every other 16-row group. 2-deep acc pipeline: per group j
// {prefetch af(j+1) | 8 MFMA into CUR (INITC as C-in, no init movs) |
//  drain PREV's 16 exp2}. setprio brackets the MFMA cluster (v13-proven).
__global__ __launch_bounds__(256, 2) void lse_kernel(const int* __restrict__ Mp,
                                                     const int* __restrict__ z8,
                                                     float* __restrict__ lsep) {
  const int bid = blockIdx.x;             // 512 blocks
  const int xcd = bid & 7;
  const int g = bid >> 3;                 // 0..63
  const int bblk = g & 31;
  const int half = g >> 5;
  const int nsplit = xcd * 2 + half;      // 2 ranges live per XCD

  const int tid = threadIdx.x;
  const int w = tid >> 6;
  const int lane = tid & 63;
  const int l15 = lane & 15;
  const int grp = lane >> 4;
  const int bh = w & 1;                   // b-half (64 cols = 4 bt x 16)
  const int nh = w >> 1;                  // group parity

  // hoist z fragments: 4 b-subtiles x 2 k-halves = 64 regs
  v8i zf[4][2];
  const int brow0 = bblk * BBLK + bh * 64;
  #pragma unroll
  for (int bt = 0; bt < 4; ++bt) {
    #pragma unroll
    for (int kh = 0; kh < 2; ++kh) {
      int row = brow0 + bt * 16 + l15;
      zf[bt][kh] = *(const v8i*)(z8 + (size_t)row * 64 + kh * 32 + grp * 8);
    }
  }

  // fragment stream: s = nsplit*256 + nh + 2*j; dword(s,kh,lane)=s*1024+kh*512+lane*8
  const int* pj = Mp + (size_t)(nsplit * SPR + nh) * 1024 + lane * 8;

  const f32x4 INITC = {-SHIFT2, -SHIFT2, -SHIFT2, -SHIFT2};
  float ssum[4] = {0.f, 0.f, 0.f, 0.f};
  f32x4 accA[4], accB[4];
  v8i afA[2], afB[2];

  // accB pre-drained state: -inf so the first (dummy) drain adds exp2(-inf)=0
  #pragma unroll
  for (int bt = 0; bt < 4; ++bt)
    #pragma unroll
    for (int q = 0; q < 4; ++q) accB[bt][q] = -INFINITY;

  // prologue: group 0's fragments in flight
  #pragma unroll
  for (int kh = 0; kh < 2; ++kh) afA[kh] = *(const v8i*)(pj + kh * 512);

  // body: prefetch next group's frags into NXTF, compute CURF into CUR
  // (INITC as kh=0 C-in), drain PREV on the trans pipe
  auto body = [&](f32x4 (&CUR)[4], f32x4 (&PREV)[4], v8i (&CURF)[2], v8i (&NXTF)[2]) {
    const int* pn = pj + 2048;            // next group (s += 2)
    #pragma unroll
    for (int kh = 0; kh < 2; ++kh) NXTF[kh] = *(const v8i*)(pn + kh * 512);

    __builtin_amdgcn_s_setprio(1);
    #pragma unroll
    for (int bt = 0; bt < 4; ++bt)        // kh=0: INITC as C-in (no init movs)
      CUR[bt] = __builtin_amdgcn_mfma_scale_f32_16x16x128_f8f6f4(
          CURF[0], zf[bt][0], INITC, 0, 0, 0, SCL1, 0, SCL1);
    #pragma unroll
    for (int bt = 0; bt < 4; ++bt)        // kh=1: accumulate
      CUR[bt] = __builtin_amdgcn_mfma_scale_f32_16x16x128_f8f6f4(
          CURF[1], zf[bt][1], CUR[bt], 0, 0, 0, SCL1, 0, SCL1);
    __builtin_amdgcn_s_setprio(0);

    // drain PREVIOUS group's accumulator (independent of in-flight MFMAs)
    #pragma unroll
    for (int bt = 0; bt < 4; ++bt)
      ssum[bt] += (fexp2(PREV[bt][0]) + fexp2(PREV[bt][1])) +
                  (fexp2(PREV[bt][2]) + fexp2(PREV[bt][3]));

    pj = pn;
  };

  #pragma unroll 1
  for (int jp = 0; jp < SPERW / 2; ++jp) {
    body(accA, accB, afA, afB);   // even: compute A (frags A), drain B
    body(accB, accA, afB, afA);   // odd:  compute B (frags B), drain A
  }
  // (tail prefetch overshoots into the z8 region of d_ws: harmless)

  // final drain (accB computed last)
  #pragma unroll
  for (int bt = 0; bt < 4; ++bt)
    ssum[bt] += (fexp2(accB[bt][0]) + fexp2(accB[bt][1])) +
                (fexp2(accB[bt][2]) + fexp2(accB[bt][3]));

  // 4 lane-groups hold different n-rows of each fragment for the same b-col
  #pragma unroll
  for (int bt = 0; bt < 4; ++bt) {
    ssum[bt] += __shfl_xor(ssum[bt], 16, 64);
    ssum[bt] += __shfl_xor(ssum[bt], 32, 64);
  }
  if (grp == 0) {
    #pragma unroll
    for (int bt = 0; bt < 4; ++bt) {
      int b = brow0 + bt * 16 + l15;
      lsep[(size_t)b * NPART + nsplit * 2 + nh] = ssum[bt];
    }
  }
}

// ---------------------------------------------------------------- kernel C1
// per-row logsumexp partial combine (parallel: 16 blocks x 256 = 4096 rows)
__global__ void rowlse_kernel(const float* __restrict__ lsep, float* __restrict__ rowlse) {
  int r = blockIdx.x * 256 + threadIdx.x;
  float S = 0.f;
  #pragma unroll
  for (int i = 0; i < NPART; ++i) S += lsep[(size_t)r * NPART + i];
  rowlse[r] = SHIFT2 * LN2 + logf(S);
}

// ---------------------------------------------------------------- kernel C2
__global__ void finalize_kernel(const float* __restrict__ rowlse, const float* __restrict__ css,
                                const float* __restrict__ zss, float* __restrict__ out) {
  __shared__ float r1[16], r2[16], r3[16];
  int tid = threadIdx.x;  // 1024
  float sum_lse = 0.f;
  #pragma unroll
  for (int i = 0; i < 4; ++i) sum_lse += rowlse[tid + i * 1024];
  float cs = 0.f, zs = 0.f;
  if (tid < 512) { cs = css[tid]; zs = zss[tid]; }

  sum_lse = waveRedAdd(sum_lse);
  cs = waveRedAdd(cs);
  zs = waveRedAdd(zs);
  int w = tid >> 6, lane = tid & 63;
  if (lane == 0) { r1[w] = sum_lse; r2[w] = cs; r3[w] = zs; }
  __syncthreads();
  if (tid == 0) {
    float sl = 0.f, sc = 0.f, sz = 0.f;
    #pragma unroll
    for (int i = 0; i < 16; ++i) { sl += r1[i]; sc += r2[i]; sz += r3[i]; }
    float hop = -sl / (float)B_ROWS;
    float cons = sc / (float)B_ROWS;
    float reg = 0.01f * sz / (float)B_ROWS;
    out[0] = hop + cons + reg;
    out[1] = hop;
    out[2] = cons;
    out[3] = reg;
  }
}

// ---------------------------------------------------------------------------
extern "C" void kernel_launch(void* const* d_in, const int* in_sizes, int n_in,
                              void* d_out, int out_size, void* d_ws, size_t ws_size,
                              hipStream_t stream) {
  (void)in_sizes; (void)n_in; (void)out_size; (void)ws_size;
  const float* z  = (const float*)d_in[0];
  const float* zn = (const float*)d_in[1];
  const float* M  = (const float*)d_in[2];
  char* ws = (char*)d_ws;
  int* Mp  = (int*)(ws + WS_M_OFF);
  int* z8  = (int*)(ws + WS_Z_OFF);
  float* lsep = (float*)(ws + WS_LSE_OFF);
  float* rowlse = (float*)(ws + WS_ROW_OFF);
  float* css = (float*)(ws + WS_CSS_OFF);
  float* zss = (float*)(ws + WS_ZSS_OFF);

  convert_m_kernel<<<8192, 256, 0, stream>>>(M, Mp);
  prep_z_kernel<<<512, 256, 0, stream>>>(z, zn, z8, css, zss);
  lse_kernel<<<512, 256, 0, stream>>>(Mp, z8, lsep);
  rowlse_kernel<<<16, 256, 0, stream>>>(lsep, rowlse);
  finalize_kernel<<<1, 1024, 0, stream>>>(rowlse, css, zss, (float*)d_out);
}